// Round 1
// baseline (105.350 us; speedup 1.0000x reference)
//
#include <hip/hip_runtime.h>
#include <math.h>

#define NB 64
#define NT 4096
#define NU 512
#define NL 128
#define HALF 64

#define BM 64
#define BN 128
#define BK 64
#define ASTRIDE 68   // BM + 4: keeps float4 LDS reads 16B-aligned, breaks pow2 bank stride

// ---------------- Kernel 1: q2[b][v] = query[b] @ W2[:,v] + b2[v] + b1[v] ----------
__global__ __launch_bounds__(256) void k_q2(const float* __restrict__ query,
                                            const float* __restrict__ W2,
                                            const float* __restrict__ b2,
                                            const float* __restrict__ b1,
                                            float* __restrict__ q2) {
    const int b = blockIdx.x, tid = threadIdx.x;
    __shared__ float qs[NU];
    qs[tid]       = query[b * NU + tid];
    qs[tid + 256] = query[b * NU + tid + 256];
    __syncthreads();
    float a0 = 0.f, a1 = 0.f;
    const float* w = W2 + tid;
    #pragma unroll 8
    for (int u = 0; u < NU; ++u) {
        const float q = qs[u];
        a0 = fmaf(q, w[(size_t)u * NU], a0);
        a1 = fmaf(q, w[(size_t)u * NU + 256], a1);
    }
    q2[b * NU + tid]       = a0 + b2[tid] + b1[tid];
    q2[b * NU + tid + 256] = a1 + b2[tid + 256] + b1[tid + 256];
}

// ---------------- Kernel 2: scores via tiled GEMM + tanh + V-reduce -----------------
// grid (B*NL/BM = 128, NU/BN = 4), 256 threads.
// part[nb][b][l] = sum over v in [nb*128, nb*128+128) of tanh(G[b,l,v]+q2[b,v])*V[v]
__global__ __launch_bounds__(256) void k_score(const float* __restrict__ values,
                                               const int* __restrict__ pos,
                                               const float* __restrict__ W1,
                                               const float* __restrict__ V,
                                               const float* __restrict__ q2,
                                               float* __restrict__ part) {
    __shared__ float As[BK][ASTRIDE];   // A^T tile: [k][row]
    __shared__ float Bs[BK][BN];        // W1 tile:  [k][col]

    const int rb = blockIdx.x;          // 0..127 : (b, half)
    const int nb = blockIdx.y;          // 0..3
    const int b  = rb >> 1;
    const int l0 = (rb & 1) * BM;
    const int n0 = nb * BN;
    const int tid = threadIdx.x;
    const int tx = tid & 15;            // col group: 8 cols each
    const int ty = tid >> 4;            // row group: 4 rows each

    const int p     = pos[b];
    const int start = max(p - HALF, 0);
    const int xlen  = min(p + HALF, NT) - start;

    const float* vbase = values + ((size_t)b * NT + start) * NU;

    float acc[4][8];
    #pragma unroll
    for (int r = 0; r < 4; ++r)
        #pragma unroll
        for (int c = 0; c < 8; ++c) acc[r][c] = 0.f;

    for (int k0 = 0; k0 < NU; k0 += BK) {
        // stage A (64 rows x 64 k), transposed into As[k][row], zero-fill masked rows
        #pragma unroll
        for (int i = 0; i < 4; ++i) {
            const int f   = tid + i * 256;   // 0..1023 float4 slots
            const int row = f >> 4;          // 0..63
            const int kq  = f & 15;          // float4 within row
            const int l   = l0 + row;
            float4 v4 = make_float4(0.f, 0.f, 0.f, 0.f);
            if (l < xlen)
                v4 = *(const float4*)&vbase[(size_t)l * NU + k0 + kq * 4];
            As[kq * 4 + 0][row] = v4.x;
            As[kq * 4 + 1][row] = v4.y;
            As[kq * 4 + 2][row] = v4.z;
            As[kq * 4 + 3][row] = v4.w;
        }
        // stage B (64 k x 128 cols)
        #pragma unroll
        for (int i = 0; i < 8; ++i) {
            const int f  = tid + i * 256;    // 0..2047 float4 slots
            const int kk = f >> 5;
            const int nq = f & 31;
            *(float4*)&Bs[kk][nq * 4] =
                *(const float4*)&W1[(size_t)(k0 + kk) * NU + n0 + nq * 4];
        }
        __syncthreads();

        #pragma unroll 16
        for (int kk = 0; kk < BK; ++kk) {
            const float4 a  = *(const float4*)&As[kk][ty * 4];
            const float4 b0 = *(const float4*)&Bs[kk][tx * 8];
            const float4 b1v = *(const float4*)&Bs[kk][tx * 8 + 4];
            const float av[4] = {a.x, a.y, a.z, a.w};
            const float bv[8] = {b0.x, b0.y, b0.z, b0.w, b1v.x, b1v.y, b1v.z, b1v.w};
            #pragma unroll
            for (int r = 0; r < 4; ++r)
                #pragma unroll
                for (int c = 0; c < 8; ++c)
                    acc[r][c] = fmaf(av[r], bv[c], acc[r][c]);
        }
        __syncthreads();
    }

    // epilogue: tanh(acc + q2) * V, reduce over this block's 128 columns
    float partial[4] = {0.f, 0.f, 0.f, 0.f};
    #pragma unroll
    for (int c = 0; c < 8; ++c) {
        const int v = n0 + tx * 8 + c;
        const float vv = V[v];
        const float qq = q2[b * NU + v];
        #pragma unroll
        for (int r = 0; r < 4; ++r)
            partial[r] += tanhf(acc[r][c] + qq) * vv;
    }
    #pragma unroll
    for (int off = 1; off < 16; off <<= 1)
        #pragma unroll
        for (int r = 0; r < 4; ++r)
            partial[r] += __shfl_xor(partial[r], off, 16);

    if (tx == 0) {
        #pragma unroll
        for (int r = 0; r < 4; ++r) {
            const int l = l0 + ty * 4 + r;
            part[((size_t)nb * NB + b) * NL + l] = partial[r];
        }
    }
}

// ---------------- Kernel 3: softmax over L + context ------------------------------
__global__ __launch_bounds__(256) void k_ctx(const float* __restrict__ values,
                                             const int* __restrict__ pos,
                                             const float* __restrict__ part,
                                             const float* __restrict__ bV,
                                             float* __restrict__ out) {
    const int b = blockIdx.x, tid = threadIdx.x;
    __shared__ float w[NL];
    __shared__ float red[4];

    float s = -1e30f;
    if (tid < NL) {
        s = bV[0];
        #pragma unroll
        for (int nb = 0; nb < 4; ++nb) s += part[((size_t)nb * NB + b) * NL + tid];
    }
    // max over 128 scores (waves 0 and 1)
    float m = s;
    #pragma unroll
    for (int off = 32; off >= 1; off >>= 1) m = fmaxf(m, __shfl_xor(m, off, 64));
    if (tid < NL && (tid & 63) == 0) red[tid >> 6] = m;
    __syncthreads();
    const float M = fmaxf(red[0], red[1]);
    const float e = (tid < NL) ? expf(s - M) : 0.f;
    float t = e;
    #pragma unroll
    for (int off = 32; off >= 1; off >>= 1) t += __shfl_xor(t, off, 64);
    if (tid < NL && (tid & 63) == 0) red[2 + (tid >> 6)] = t;
    __syncthreads();
    const float S = red[2] + red[3];
    if (tid < NL) w[tid] = e / S;
    __syncthreads();

    if (tid < NL) out[NB * NU + b * NL + tid] = w[tid];

    const int p     = pos[b];
    const int start = max(p - HALF, 0);
    const int xlen  = min(p + HALF, NT) - start;
    const float* vb = values + ((size_t)b * NT + start) * NU;

    float a0 = 0.f, a1 = 0.f;
    for (int l = 0; l < xlen; ++l) {
        const float wl = w[l];
        a0 = fmaf(wl, vb[(size_t)l * NU + tid], a0);
        a1 = fmaf(wl, vb[(size_t)l * NU + tid + 256], a1);
    }
    out[b * NU + tid]       = a0;
    out[b * NU + tid + 256] = a1;
}

// ---------------- launch -----------------------------------------------------------
extern "C" void kernel_launch(void* const* d_in, const int* in_sizes, int n_in,
                              void* d_out, int out_size, void* d_ws, size_t ws_size,
                              hipStream_t stream) {
    const float* query  = (const float*)d_in[0];
    const float* values = (const float*)d_in[1];
    const int*   pos    = (const int*)d_in[2];
    const float* W1     = (const float*)d_in[3];
    const float* b1     = (const float*)d_in[4];
    const float* W2     = (const float*)d_in[5];
    const float* b2     = (const float*)d_in[6];
    const float* V      = (const float*)d_in[7];
    const float* bV     = (const float*)d_in[8];
    float* out = (float*)d_out;

    float* q2   = (float*)d_ws;          // NB*NU floats = 128 KB
    float* part = q2 + NB * NU;          // 4*NB*NL floats = 128 KB

    k_q2<<<NB, 256, 0, stream>>>(query, W2, b2, b1, q2);
    k_score<<<dim3(NB * NL / BM, NU / BN), 256, 0, stream>>>(values, pos, W1, V, q2, part);
    k_ctx<<<NB, 256, 0, stream>>>(values, pos, part, bV, out);
}

// Round 2
// 63.794 us; speedup vs baseline: 1.6514x; 1.6514x over previous
//
#include <hip/hip_runtime.h>
#include <math.h>

#define NB 64
#define NT 4096
#define NU 512
#define NL 128
#define HALF 64

typedef __bf16 bf16x8 __attribute__((ext_vector_type(8)));
typedef float f32x4 __attribute__((ext_vector_type(4)));

__device__ inline unsigned short f2bf(float f) {
    unsigned u = __float_as_uint(f);
    u += 0x7fff + ((u >> 16) & 1);   // RNE
    return (unsigned short)(u >> 16);
}

// =====================================================================
// FAST PATH (bf16 MFMA)
// =====================================================================

// Prep: blocks 0..63 -> q2[b] = query@W2 + b2 + b1  (fp32)
//       blocks 64..575 -> gather windows -> bf16 Gb[b][l][u], zero-filled
//       blocks 576..831 -> W1 -> W1T bf16 (tiled transpose)
__global__ __launch_bounds__(256) void k_prep(const float* __restrict__ query,
                                              const float* __restrict__ values,
                                              const int* __restrict__ pos,
                                              const float* __restrict__ W1,
                                              const float* __restrict__ b1,
                                              const float* __restrict__ W2,
                                              const float* __restrict__ b2,
                                              float* __restrict__ q2,
                                              unsigned short* __restrict__ W1T,
                                              unsigned short* __restrict__ Gb) {
    __shared__ float sh[1056];
    const int blk = blockIdx.x, tid = threadIdx.x;

    if (blk < NB) {
        // ---- q2 ----
        sh[tid]       = query[blk * NU + tid];
        sh[tid + 256] = query[blk * NU + tid + 256];
        __syncthreads();
        float a0 = 0.f, a1 = 0.f;
        const float* wp = W2 + tid;
        #pragma unroll 8
        for (int u = 0; u < NU; ++u) {
            const float q = sh[u];
            a0 = fmaf(q, wp[(size_t)u * NU], a0);
            a1 = fmaf(q, wp[(size_t)u * NU + 256], a1);
        }
        q2[blk * NU + tid]       = a0 + b2[tid] + b1[tid];
        q2[blk * NU + tid + 256] = a1 + b2[tid + 256] + b1[tid + 256];
    } else if (blk < NB + 512) {
        // ---- gather + bf16 convert ----
        const int g = blk - NB;              // 0..511, 16 rows each
        #pragma unroll
        for (int i = 0; i < 8; ++i) {
            const int c   = tid + i * 256;   // 0..2047 float4 chunks
            const int rl  = c >> 7;          // 0..15
            const int off = (c & 127) * 4;
            const int rg  = g * 16 + rl;     // global row in [0, 8192)
            const int b   = rg >> 7, l = rg & 127;
            const int p     = pos[b];
            const int start = max(p - HALF, 0);
            const int xlen  = min(p + HALF, NT) - start;
            float4 v = make_float4(0.f, 0.f, 0.f, 0.f);
            if (l < xlen)
                v = *(const float4*)&values[((size_t)(b * NT + start + l)) * NU + off];
            uint2 pk;
            pk.x = f2bf(v.x) | ((unsigned)f2bf(v.y) << 16);
            pk.y = f2bf(v.z) | ((unsigned)f2bf(v.w) << 16);
            *(uint2*)&Gb[(size_t)rg * NU + off] = pk;
        }
    } else {
        // ---- W1 transpose -> bf16 ----
        const int t  = blk - NB - 512;       // 0..255 : 16x16 grid of 32x32 tiles
        const int tr = t >> 4, tc = t & 15;
        const int cc = tid & 31, r0 = tid >> 5;
        #pragma unroll
        for (int i = 0; i < 4; ++i) {
            const int r = r0 + i * 8;
            sh[r * 33 + cc] = W1[(size_t)(tr * 32 + r) * NU + tc * 32 + cc];
        }
        __syncthreads();
        #pragma unroll
        for (int i = 0; i < 4; ++i) {
            const int r = r0 + i * 8;
            W1T[(size_t)(tc * 32 + r) * NU + tr * 32 + cc] = f2bf(sh[cc * 33 + r]);
        }
    }
}

// Score GEMM: grid (128, 4), 256 threads = 4 waves.
// Block: 64 rows (l0..l0+63) x 128 cols (n0..n0+127), K=512.
// Wave w: rows w*16..w*16+15 x all 128 cols -> row sums stay in-wave.
__global__ __launch_bounds__(256) void k_score_mfma(const unsigned short* __restrict__ Gb,
                                                    const unsigned short* __restrict__ W1T,
                                                    const float* __restrict__ V,
                                                    const float* __restrict__ q2,
                                                    float* __restrict__ part) {
    __shared__ unsigned short As[64 * 64];    // [row][k], XOR-swizzled 16B blocks
    __shared__ unsigned short Bs[128 * 64];   // [col][k], XOR-swizzled 16B blocks

    const int rb = blockIdx.x, nb = blockIdx.y;
    const int b = rb >> 1, l0 = (rb & 1) * 64, n0 = nb * 128;
    const int tid = threadIdx.x, lane = tid & 63, w = tid >> 6;

    f32x4 acc[8];
    #pragma unroll
    for (int i = 0; i < 8; ++i) acc[i] = (f32x4){0.f, 0.f, 0.f, 0.f};

    const unsigned short* Asrc = Gb + ((size_t)(b * NL + l0)) * NU;
    const unsigned short* Bsrc = W1T + (size_t)n0 * NU;

    for (int k0 = 0; k0 < NU; k0 += 64) {
        #pragma unroll
        for (int i = 0; i < 2; ++i) {         // A: 512 x 16B chunks
            const int c = tid + i * 256;
            const int row = c >> 3, kc = (c & 7) * 8;
            uint4 v = *(const uint4*)&Asrc[(size_t)row * NU + k0 + kc];
            *(uint4*)((char*)As + row * 128 + ((kc * 2) ^ ((row & 7) << 4))) = v;
        }
        #pragma unroll
        for (int i = 0; i < 4; ++i) {         // B: 1024 x 16B chunks
            const int c = tid + i * 256;
            const int col = c >> 3, kc = (c & 7) * 8;
            uint4 v = *(const uint4*)&Bsrc[(size_t)col * NU + k0 + kc];
            *(uint4*)((char*)Bs + col * 128 + ((kc * 2) ^ ((col & 7) << 4))) = v;
        }
        __syncthreads();

        #pragma unroll
        for (int ks = 0; ks < 2; ++ks) {
            const int kk = ks * 32 + (lane >> 4) * 8;
            const int rowA = (w << 4) + (lane & 15);
            const bf16x8 af = *(const bf16x8*)((const char*)As + rowA * 128 + ((kk * 2) ^ ((rowA & 7) << 4)));
            #pragma unroll
            for (int nf = 0; nf < 8; ++nf) {
                const int colB = (nf << 4) + (lane & 15);
                const bf16x8 bf = *(const bf16x8*)((const char*)Bs + colB * 128 + ((kk * 2) ^ ((colB & 7) << 4)));
                acc[nf] = __builtin_amdgcn_mfma_f32_16x16x32_bf16(af, bf, acc[nf], 0, 0, 0);
            }
        }
        __syncthreads();
    }

    // epilogue: partial[l] = sum_cols tanh(acc + q2[col]) * V[col]
    float partial[4] = {0.f, 0.f, 0.f, 0.f};
    #pragma unroll
    for (int nf = 0; nf < 8; ++nf) {
        const int col = n0 + (nf << 4) + (lane & 15);
        const float qq = q2[b * NU + col];
        const float vv = V[col];
        #pragma unroll
        for (int r = 0; r < 4; ++r)
            partial[r] += tanhf(acc[nf][r] + qq) * vv;
    }
    #pragma unroll
    for (int off = 1; off < 16; off <<= 1)
        #pragma unroll
        for (int r = 0; r < 4; ++r)
            partial[r] += __shfl_xor(partial[r], off, 16);

    if ((lane & 15) == 0) {
        #pragma unroll
        for (int r = 0; r < 4; ++r) {
            const int l = l0 + (w << 4) + ((lane >> 4) << 2) + r;
            part[((size_t)nb * NB + b) * NL + l] = partial[r];
        }
    }
}

// =====================================================================
// FALLBACK PATH (proven fp32) — used only if ws too small
// =====================================================================
#define BM 64
#define BN 128
#define BK 64
#define ASTRIDE 68

__global__ __launch_bounds__(256) void k_q2(const float* __restrict__ query,
                                            const float* __restrict__ W2,
                                            const float* __restrict__ b2,
                                            const float* __restrict__ b1,
                                            float* __restrict__ q2) {
    const int b = blockIdx.x, tid = threadIdx.x;
    __shared__ float qs[NU];
    qs[tid]       = query[b * NU + tid];
    qs[tid + 256] = query[b * NU + tid + 256];
    __syncthreads();
    float a0 = 0.f, a1 = 0.f;
    const float* w = W2 + tid;
    #pragma unroll 8
    for (int u = 0; u < NU; ++u) {
        const float q = qs[u];
        a0 = fmaf(q, w[(size_t)u * NU], a0);
        a1 = fmaf(q, w[(size_t)u * NU + 256], a1);
    }
    q2[b * NU + tid]       = a0 + b2[tid] + b1[tid];
    q2[b * NU + tid + 256] = a1 + b2[tid + 256] + b1[tid + 256];
}

__global__ __launch_bounds__(256) void k_score(const float* __restrict__ values,
                                               const int* __restrict__ pos,
                                               const float* __restrict__ W1,
                                               const float* __restrict__ V,
                                               const float* __restrict__ q2,
                                               float* __restrict__ part) {
    __shared__ float As[BK][ASTRIDE];
    __shared__ float Bs[BK][BN];
    const int rb = blockIdx.x, nb = blockIdx.y;
    const int b  = rb >> 1;
    const int l0 = (rb & 1) * BM;
    const int n0 = nb * BN;
    const int tid = threadIdx.x;
    const int tx = tid & 15, ty = tid >> 4;
    const int p     = pos[b];
    const int start = max(p - HALF, 0);
    const int xlen  = min(p + HALF, NT) - start;
    const float* vbase = values + ((size_t)b * NT + start) * NU;

    float acc[4][8];
    #pragma unroll
    for (int r = 0; r < 4; ++r)
        #pragma unroll
        for (int c = 0; c < 8; ++c) acc[r][c] = 0.f;

    for (int k0 = 0; k0 < NU; k0 += BK) {
        #pragma unroll
        for (int i = 0; i < 4; ++i) {
            const int f = tid + i * 256;
            const int row = f >> 4, kq = f & 15;
            const int l = l0 + row;
            float4 v4 = make_float4(0.f, 0.f, 0.f, 0.f);
            if (l < xlen)
                v4 = *(const float4*)&vbase[(size_t)l * NU + k0 + kq * 4];
            As[kq * 4 + 0][row] = v4.x;
            As[kq * 4 + 1][row] = v4.y;
            As[kq * 4 + 2][row] = v4.z;
            As[kq * 4 + 3][row] = v4.w;
        }
        #pragma unroll
        for (int i = 0; i < 8; ++i) {
            const int f = tid + i * 256;
            const int kk = f >> 5, nq = f & 31;
            *(float4*)&Bs[kk][nq * 4] =
                *(const float4*)&W1[(size_t)(k0 + kk) * NU + n0 + nq * 4];
        }
        __syncthreads();
        #pragma unroll 16
        for (int kk = 0; kk < BK; ++kk) {
            const float4 a  = *(const float4*)&As[kk][ty * 4];
            const float4 b0 = *(const float4*)&Bs[kk][tx * 8];
            const float4 b1v = *(const float4*)&Bs[kk][tx * 8 + 4];
            const float av[4] = {a.x, a.y, a.z, a.w};
            const float bv[8] = {b0.x, b0.y, b0.z, b0.w, b1v.x, b1v.y, b1v.z, b1v.w};
            #pragma unroll
            for (int r = 0; r < 4; ++r)
                #pragma unroll
                for (int c = 0; c < 8; ++c)
                    acc[r][c] = fmaf(av[r], bv[c], acc[r][c]);
        }
        __syncthreads();
    }
    float partial[4] = {0.f, 0.f, 0.f, 0.f};
    #pragma unroll
    for (int c = 0; c < 8; ++c) {
        const int v = n0 + tx * 8 + c;
        const float vv = V[v];
        const float qq = q2[b * NU + v];
        #pragma unroll
        for (int r = 0; r < 4; ++r)
            partial[r] += tanhf(acc[r][c] + qq) * vv;
    }
    #pragma unroll
    for (int off = 1; off < 16; off <<= 1)
        #pragma unroll
        for (int r = 0; r < 4; ++r)
            partial[r] += __shfl_xor(partial[r], off, 16);
    if (tx == 0) {
        #pragma unroll
        for (int r = 0; r < 4; ++r) {
            const int l = l0 + ty * 4 + r;
            part[((size_t)nb * NB + b) * NL + l] = partial[r];
        }
    }
}

// =====================================================================
// Softmax + context (shared by both paths)
// =====================================================================
__global__ __launch_bounds__(256) void k_ctx(const float* __restrict__ values,
                                             const int* __restrict__ pos,
                                             const float* __restrict__ part,
                                             const float* __restrict__ bV,
                                             float* __restrict__ out) {
    const int b = blockIdx.x, tid = threadIdx.x;
    __shared__ float w[NL];
    __shared__ float red[4];

    float s = -1e30f;
    if (tid < NL) {
        s = bV[0];
        #pragma unroll
        for (int nb = 0; nb < 4; ++nb) s += part[((size_t)nb * NB + b) * NL + tid];
    }
    float m = s;
    #pragma unroll
    for (int off = 32; off >= 1; off >>= 1) m = fmaxf(m, __shfl_xor(m, off, 64));
    if (tid < NL && (tid & 63) == 0) red[tid >> 6] = m;
    __syncthreads();
    const float M = fmaxf(red[0], red[1]);
    const float e = (tid < NL) ? expf(s - M) : 0.f;
    float t = e;
    #pragma unroll
    for (int off = 32; off >= 1; off >>= 1) t += __shfl_xor(t, off, 64);
    if (tid < NL && (tid & 63) == 0) red[2 + (tid >> 6)] = t;
    __syncthreads();
    const float S = red[2] + red[3];
    if (tid < NL) w[tid] = e / S;
    __syncthreads();

    if (tid < NL) out[NB * NU + b * NL + tid] = w[tid];

    const int p     = pos[b];
    const int start = max(p - HALF, 0);
    const int xlen  = min(p + HALF, NT) - start;
    const float* vb = values + ((size_t)b * NT + start) * NU;

    float a0 = 0.f, a1 = 0.f;
    for (int l = 0; l < xlen; ++l) {
        const float wl = w[l];
        a0 = fmaf(wl, vb[(size_t)l * NU + tid], a0);
        a1 = fmaf(wl, vb[(size_t)l * NU + tid + 256], a1);
    }
    out[b * NU + tid]       = a0;
    out[b * NU + tid + 256] = a1;
}

// =====================================================================
extern "C" void kernel_launch(void* const* d_in, const int* in_sizes, int n_in,
                              void* d_out, int out_size, void* d_ws, size_t ws_size,
                              hipStream_t stream) {
    const float* query  = (const float*)d_in[0];
    const float* values = (const float*)d_in[1];
    const int*   pos    = (const int*)d_in[2];
    const float* W1     = (const float*)d_in[3];
    const float* b1     = (const float*)d_in[4];
    const float* W2     = (const float*)d_in[5];
    const float* b2     = (const float*)d_in[6];
    const float* V      = (const float*)d_in[7];
    const float* bV     = (const float*)d_in[8];
    float* out = (float*)d_out;

    float* q2   = (float*)d_ws;                                    // 128 KB
    float* part = (float*)((char*)d_ws + 131072);                  // 128 KB

    const size_t need = 131072u + 131072u + 524288u + 8388608u;    // ~9.2 MB
    if (ws_size >= need) {
        unsigned short* W1T = (unsigned short*)((char*)d_ws + 262144);
        unsigned short* Gb  = (unsigned short*)((char*)d_ws + 786432);
        k_prep<<<NB + 512 + 256, 256, 0, stream>>>(query, values, pos, W1, b1, W2, b2,
                                                   q2, W1T, Gb);
        k_score_mfma<<<dim3(NB * NL / 64, NU / 128), 256, 0, stream>>>(Gb, W1T, V, q2, part);
    } else {
        k_q2<<<NB, 256, 0, stream>>>(query, W2, b2, b1, q2);
        k_score<<<dim3(NB * NL / BM, NU / BN), 256, 0, stream>>>(values, pos, W1, V, q2, part);
    }
    k_ctx<<<NB, 256, 0, stream>>>(values, pos, part, bV, out);
}

// Round 3
// 46.690 us; speedup vs baseline: 2.2564x; 1.3663x over previous
//
#include <hip/hip_runtime.h>
#include <math.h>

#define NB 64
#define NT 4096
#define NU 512
#define NL 128
#define HALF 64

typedef __bf16 bf16x8 __attribute__((ext_vector_type(8)));
typedef float f32x4 __attribute__((ext_vector_type(4)));

__device__ inline unsigned short f2bf(float f) {
    unsigned u = __float_as_uint(f);
    u += 0x7fff + ((u >> 16) & 1);   // RNE
    return (unsigned short)(u >> 16);
}

__device__ inline float tanh_fast(float x) {
    float xc = fminf(15.f, fmaxf(-15.f, x));
    float t = __expf(2.f * xc);                       // v_exp_f32 path
    return (t - 1.f) * __builtin_amdgcn_rcpf(t + 1.f);
}

// =====================================================================
// Prep: blocks 0..255   -> q2 quarters: q2p[kq][b][c] = sum_{u in quarter} q[u]W2[u][c]
//       blocks 256..511 -> W1 -> W1T bf16 (32x32 tiled transpose)
// =====================================================================
__global__ __launch_bounds__(256) void k_prep2(const float* __restrict__ query,
                                               const float* __restrict__ W1,
                                               const float* __restrict__ b1,
                                               const float* __restrict__ W2,
                                               const float* __restrict__ b2,
                                               float* __restrict__ q2p,
                                               unsigned short* __restrict__ W1T) {
    __shared__ float sh[1056];
    const int blk = blockIdx.x, tid = threadIdx.x;

    if (blk < 256) {
        const int b = blk >> 2, kq = blk & 3;
        if (tid < 128) sh[tid] = query[b * NU + kq * 128 + tid];
        __syncthreads();
        float a0 = 0.f, a1 = 0.f;
        const float* wp = W2 + (size_t)(kq * 128) * NU + tid;
        #pragma unroll 8
        for (int u = 0; u < 128; ++u) {
            const float q = sh[u];
            a0 = fmaf(q, wp[(size_t)u * NU], a0);
            a1 = fmaf(q, wp[(size_t)u * NU + 256], a1);
        }
        if (kq == 0) {
            a0 += b1[tid] + b2[tid];
            a1 += b1[tid + 256] + b2[tid + 256];
        }
        q2p[((size_t)kq * NB + b) * NU + tid]       = a0;
        q2p[((size_t)kq * NB + b) * NU + tid + 256] = a1;
    } else {
        const int t  = blk - 256;            // 16x16 grid of 32x32 tiles
        const int tr = t >> 4, tc = t & 15;
        const int cc = tid & 31, r0 = tid >> 5;
        #pragma unroll
        for (int i = 0; i < 4; ++i) {
            const int r = r0 + i * 8;
            sh[r * 33 + cc] = W1[(size_t)(tr * 32 + r) * NU + tc * 32 + cc];
        }
        __syncthreads();
        #pragma unroll
        for (int i = 0; i < 4; ++i) {
            const int r = r0 + i * 8;
            W1T[(size_t)(tc * 32 + r) * NU + tr * 32 + cc] = f2bf(sh[cc * 33 + r]);
        }
    }
}

// =====================================================================
// Fused: one block per batch b. 512 threads = 8 waves (2 row-groups x 4 col-groups).
// GEMM(128x512x512, bf16 MFMA) -> tanh*V row-reduce -> softmax(128) -> context.
// =====================================================================
__global__ __launch_bounds__(512, 2) void k_fused(const float* __restrict__ values,
                                                  const int* __restrict__ pos,
                                                  const unsigned short* __restrict__ W1T,
                                                  const float* __restrict__ q2p,
                                                  const float* __restrict__ V,
                                                  const float* __restrict__ bV,
                                                  float* __restrict__ out) {
    __shared__ unsigned short As[NL * 32];   // 8 KB  [row][k], 64B rows, XOR-swizzled
    __shared__ unsigned short Bs[NU * 32];   // 32 KB [col][k], 64B rows, XOR-swizzled
    __shared__ float q2s[NU];
    __shared__ float vsh[NU];
    __shared__ float pl[4][NL];
    __shared__ float wsm[NL];
    __shared__ float red[4];

    const int b    = blockIdx.x;
    const int tid  = threadIdx.x;
    const int lane = tid & 63;
    const int w    = tid >> 6;
    const int wr   = w >> 2;                 // 0..1 : 64-row group
    const int wc   = w & 3;                  // 0..3 : 128-col group

    const int p     = pos[b];
    const int start = max(p - HALF, 0);
    const int xlen  = min(p + HALF, NT) - start;
    const float* vbase = values + ((size_t)b * NT + start) * NU;

    // q2 (sum 4 K-quarters) and V into LDS
    q2s[tid] = q2p[(size_t)b * NU + tid]
             + q2p[((size_t)1 * NB + b) * NU + tid]
             + q2p[((size_t)2 * NB + b) * NU + tid]
             + q2p[((size_t)3 * NB + b) * NU + tid];
    vsh[tid] = V[tid];

    f32x4 acc[4][8];
    #pragma unroll
    for (int m = 0; m < 4; ++m)
        #pragma unroll
        for (int n = 0; n < 8; ++n) acc[m][n] = (f32x4){0.f, 0.f, 0.f, 0.f};

    const int kk2 = (lane >> 4) * 16;        // byte offset of this lane-group's 8 bf16

    for (int k0 = 0; k0 < NU; k0 += 32) {
        // stage A: 128 rows x 32 k fp32 -> bf16, zero-fill masked rows
        #pragma unroll
        for (int i = 0; i < 2; ++i) {
            const int c   = tid + i * 512;   // 0..1023 float4 chunks
            const int row = c >> 3, kq = c & 7;
            float4 v = make_float4(0.f, 0.f, 0.f, 0.f);
            if (row < xlen)
                v = *(const float4*)&vbase[(size_t)row * NU + k0 + kq * 4];
            uint2 pk;
            pk.x = f2bf(v.x) | ((unsigned)f2bf(v.y) << 16);
            pk.y = f2bf(v.z) | ((unsigned)f2bf(v.w) << 16);
            *(uint2*)((char*)As + row * 64 + ((kq * 8) ^ ((row & 3) << 4))) = pk;
        }
        // stage B: 512 cols x 32 k bf16
        #pragma unroll
        for (int i = 0; i < 4; ++i) {
            const int c   = tid + i * 512;   // 0..2047 16B chunks
            const int col = c >> 2, g = c & 3;
            uint4 v = *(const uint4*)&W1T[(size_t)col * NU + k0 + g * 8];
            *(uint4*)((char*)Bs + col * 64 + ((g * 16) ^ ((col & 3) << 4))) = v;
        }
        __syncthreads();

        bf16x8 af[4];
        #pragma unroll
        for (int m = 0; m < 4; ++m) {
            const int rowA = wr * 64 + m * 16 + (lane & 15);
            af[m] = *(const bf16x8*)((const char*)As + rowA * 64 + (kk2 ^ ((rowA & 3) << 4)));
        }
        #pragma unroll
        for (int n = 0; n < 8; ++n) {
            const int colB = wc * 128 + n * 16 + (lane & 15);
            const bf16x8 bf = *(const bf16x8*)((const char*)Bs + colB * 64 + (kk2 ^ ((colB & 3) << 4)));
            #pragma unroll
            for (int m = 0; m < 4; ++m)
                acc[m][n] = __builtin_amdgcn_mfma_f32_16x16x32_bf16(af[m], bf, acc[m][n], 0, 0, 0);
        }
        __syncthreads();
    }

    // epilogue: per-row partial over this wave's 128 cols
    float partial[4][4];
    #pragma unroll
    for (int m = 0; m < 4; ++m)
        #pragma unroll
        for (int r = 0; r < 4; ++r) partial[m][r] = 0.f;

    #pragma unroll
    for (int n = 0; n < 8; ++n) {
        const int col = wc * 128 + n * 16 + (lane & 15);
        const float qq = q2s[col];
        const float vv = vsh[col];
        #pragma unroll
        for (int m = 0; m < 4; ++m)
            #pragma unroll
            for (int r = 0; r < 4; ++r)
                partial[m][r] += tanh_fast(acc[m][n][r] + qq) * vv;
    }
    #pragma unroll
    for (int off = 1; off < 16; off <<= 1)
        #pragma unroll
        for (int m = 0; m < 4; ++m)
            #pragma unroll
            for (int r = 0; r < 4; ++r)
                partial[m][r] += __shfl_xor(partial[m][r], off, 16);

    if ((lane & 15) == 0) {
        #pragma unroll
        for (int m = 0; m < 4; ++m)
            #pragma unroll
            for (int r = 0; r < 4; ++r)
                pl[wc][wr * 64 + m * 16 + ((lane >> 4) << 2) + r] = partial[m][r];
    }
    __syncthreads();

    // softmax over 128 scores (first two waves carry data; barriers are uniform)
    const float bVv = bV[0];
    float s = -1e30f;
    if (tid < NL) s = pl[0][tid] + pl[1][tid] + pl[2][tid] + pl[3][tid] + bVv;
    float mx = s;
    #pragma unroll
    for (int off = 32; off >= 1; off >>= 1) mx = fmaxf(mx, __shfl_xor(mx, off, 64));
    if (tid < NL && (tid & 63) == 0) red[tid >> 6] = mx;
    __syncthreads();
    const float M = fmaxf(red[0], red[1]);
    const float e = (tid < NL) ? __expf(s - M) : 0.f;
    float t = e;
    #pragma unroll
    for (int off = 32; off >= 1; off >>= 1) t += __shfl_xor(t, off, 64);
    if (tid < NL && (tid & 63) == 0) red[2 + (tid >> 6)] = t;
    __syncthreads();
    const float S = red[2] + red[3];
    if (tid < NL) {
        const float wv = e / S;
        wsm[tid] = wv;
        out[NB * NU + b * NL + tid] = wv;
    }
    __syncthreads();

    // context: out[b][u] = sum_{l<xlen} wsm[l] * values_window[l][u]  (fp32 exact)
    const int u = tid;
    float a0 = 0.f, a1 = 0.f;
    int l = 0;
    for (; l + 1 < xlen; l += 2) {
        a0 = fmaf(wsm[l],     vbase[(size_t)l * NU + u],       a0);
        a1 = fmaf(wsm[l + 1], vbase[(size_t)(l + 1) * NU + u], a1);
    }
    if (l < xlen) a0 = fmaf(wsm[l], vbase[(size_t)l * NU + u], a0);
    out[b * NU + u] = a0 + a1;
}

// =====================================================================
// FALLBACK PATH (proven fp32) — used only if ws too small
// =====================================================================
#define BM 64
#define BN 128
#define BK 64
#define ASTRIDE 68

__global__ __launch_bounds__(256) void k_q2(const float* __restrict__ query,
                                            const float* __restrict__ W2,
                                            const float* __restrict__ b2,
                                            const float* __restrict__ b1,
                                            float* __restrict__ q2) {
    const int b = blockIdx.x, tid = threadIdx.x;
    __shared__ float qs[NU];
    qs[tid]       = query[b * NU + tid];
    qs[tid + 256] = query[b * NU + tid + 256];
    __syncthreads();
    float a0 = 0.f, a1 = 0.f;
    const float* w = W2 + tid;
    #pragma unroll 8
    for (int u = 0; u < NU; ++u) {
        const float q = qs[u];
        a0 = fmaf(q, w[(size_t)u * NU], a0);
        a1 = fmaf(q, w[(size_t)u * NU + 256], a1);
    }
    q2[b * NU + tid]       = a0 + b2[tid] + b1[tid];
    q2[b * NU + tid + 256] = a1 + b2[tid + 256] + b1[tid + 256];
}

__global__ __launch_bounds__(256) void k_score(const float* __restrict__ values,
                                               const int* __restrict__ pos,
                                               const float* __restrict__ W1,
                                               const float* __restrict__ V,
                                               const float* __restrict__ q2,
                                               float* __restrict__ part) {
    __shared__ float As2[BK][ASTRIDE];
    __shared__ float Bs2[BK][BN];
    const int rb = blockIdx.x, nb = blockIdx.y;
    const int b  = rb >> 1;
    const int l0 = (rb & 1) * BM;
    const int n0 = nb * BN;
    const int tid = threadIdx.x;
    const int tx = tid & 15, ty = tid >> 4;
    const int p     = pos[b];
    const int start = max(p - HALF, 0);
    const int xlen  = min(p + HALF, NT) - start;
    const float* vbase = values + ((size_t)b * NT + start) * NU;

    float acc[4][8];
    #pragma unroll
    for (int r = 0; r < 4; ++r)
        #pragma unroll
        for (int c = 0; c < 8; ++c) acc[r][c] = 0.f;

    for (int k0 = 0; k0 < NU; k0 += BK) {
        #pragma unroll
        for (int i = 0; i < 4; ++i) {
            const int f = tid + i * 256;
            const int row = f >> 4, kq = f & 15;
            const int l = l0 + row;
            float4 v4 = make_float4(0.f, 0.f, 0.f, 0.f);
            if (l < xlen)
                v4 = *(const float4*)&vbase[(size_t)l * NU + k0 + kq * 4];
            As2[kq * 4 + 0][row] = v4.x;
            As2[kq * 4 + 1][row] = v4.y;
            As2[kq * 4 + 2][row] = v4.z;
            As2[kq * 4 + 3][row] = v4.w;
        }
        #pragma unroll
        for (int i = 0; i < 8; ++i) {
            const int f = tid + i * 256;
            const int kk = f >> 5, nq = f & 31;
            *(float4*)&Bs2[kk][nq * 4] =
                *(const float4*)&W1[(size_t)(k0 + kk) * NU + n0 + nq * 4];
        }
        __syncthreads();
        #pragma unroll 16
        for (int kk = 0; kk < BK; ++kk) {
            const float4 a  = *(const float4*)&As2[kk][ty * 4];
            const float4 b0 = *(const float4*)&Bs2[kk][tx * 8];
            const float4 b1v = *(const float4*)&Bs2[kk][tx * 8 + 4];
            const float av[4] = {a.x, a.y, a.z, a.w};
            const float bv[8] = {b0.x, b0.y, b0.z, b0.w, b1v.x, b1v.y, b1v.z, b1v.w};
            #pragma unroll
            for (int r = 0; r < 4; ++r)
                #pragma unroll
                for (int c = 0; c < 8; ++c)
                    acc[r][c] = fmaf(av[r], bv[c], acc[r][c]);
        }
        __syncthreads();
    }
    float partial[4] = {0.f, 0.f, 0.f, 0.f};
    #pragma unroll
    for (int c = 0; c < 8; ++c) {
        const int v = n0 + tx * 8 + c;
        const float vv = V[v];
        const float qq = q2[b * NU + v];
        #pragma unroll
        for (int r = 0; r < 4; ++r)
            partial[r] += tanhf(acc[r][c] + qq) * vv;
    }
    #pragma unroll
    for (int off = 1; off < 16; off <<= 1)
        #pragma unroll
        for (int r = 0; r < 4; ++r)
            partial[r] += __shfl_xor(partial[r], off, 16);
    if (tx == 0) {
        #pragma unroll
        for (int r = 0; r < 4; ++r) {
            const int l = l0 + ty * 4 + r;
            part[((size_t)nb * NB + b) * NL + l] = partial[r];
        }
    }
}

__global__ __launch_bounds__(256) void k_ctx(const float* __restrict__ values,
                                             const int* __restrict__ pos,
                                             const float* __restrict__ part,
                                             const float* __restrict__ bV,
                                             float* __restrict__ out) {
    const int b = blockIdx.x, tid = threadIdx.x;
    __shared__ float wsh[NL];
    __shared__ float red2[4];

    float s = -1e30f;
    if (tid < NL) {
        s = bV[0];
        #pragma unroll
        for (int nb = 0; nb < 4; ++nb) s += part[((size_t)nb * NB + b) * NL + tid];
    }
    float m = s;
    #pragma unroll
    for (int off = 32; off >= 1; off >>= 1) m = fmaxf(m, __shfl_xor(m, off, 64));
    if (tid < NL && (tid & 63) == 0) red2[tid >> 6] = m;
    __syncthreads();
    const float M = fmaxf(red2[0], red2[1]);
    const float e = (tid < NL) ? expf(s - M) : 0.f;
    float t = e;
    #pragma unroll
    for (int off = 32; off >= 1; off >>= 1) t += __shfl_xor(t, off, 64);
    if (tid < NL && (tid & 63) == 0) red2[2 + (tid >> 6)] = t;
    __syncthreads();
    const float S = red2[2] + red2[3];
    if (tid < NL) wsh[tid] = e / S;
    __syncthreads();

    if (tid < NL) out[NB * NU + b * NL + tid] = wsh[tid];

    const int p     = pos[b];
    const int start = max(p - HALF, 0);
    const int xlen  = min(p + HALF, NT) - start;
    const float* vb = values + ((size_t)b * NT + start) * NU;

    float a0 = 0.f, a1 = 0.f;
    for (int l = 0; l < xlen; ++l) {
        const float wl = wsh[l];
        a0 = fmaf(wl, vb[(size_t)l * NU + tid], a0);
        a1 = fmaf(wl, vb[(size_t)l * NU + tid + 256], a1);
    }
    out[b * NU + tid]       = a0;
    out[b * NU + tid + 256] = a1;
}

// =====================================================================
extern "C" void kernel_launch(void* const* d_in, const int* in_sizes, int n_in,
                              void* d_out, int out_size, void* d_ws, size_t ws_size,
                              hipStream_t stream) {
    const float* query  = (const float*)d_in[0];
    const float* values = (const float*)d_in[1];
    const int*   pos    = (const int*)d_in[2];
    const float* W1     = (const float*)d_in[3];
    const float* b1     = (const float*)d_in[4];
    const float* W2     = (const float*)d_in[5];
    const float* b2     = (const float*)d_in[6];
    const float* V      = (const float*)d_in[7];
    const float* bV     = (const float*)d_in[8];
    float* out = (float*)d_out;

    if (ws_size >= (1u << 20) + 4096u) {
        float* q2p          = (float*)d_ws;                           // 512 KB
        unsigned short* W1T = (unsigned short*)((char*)d_ws + 524288); // 512 KB
        k_prep2<<<512, 256, 0, stream>>>(query, W1, b1, W2, b2, q2p, W1T);
        k_fused<<<NB, 512, 0, stream>>>(values, pos, W1T, q2p, V, bV, out);
    } else {
        float* q2   = (float*)d_ws;
        float* part = (float*)((char*)d_ws + 131072);
        k_q2<<<NB, 256, 0, stream>>>(query, W2, b2, b1, q2);
        k_score<<<dim3(NB * NL / BM, NU / BN), 256, 0, stream>>>(values, pos, W1, V, q2, part);
        k_ctx<<<NB, 256, 0, stream>>>(values, pos, part, bV, out);
    }
}